// Round 4
// baseline (322.162 us; speedup 1.0000x reference)
//
#include <hip/hip_runtime.h>
#include <math.h>

// ---------------------------------------------------------------------------
// HierarchicalVAE, MI355X (gfx950), fp32 — R10: single kernel, light barrier.
// R9 post-mortem: L2/MALL weight prefetch = EXACTLY 0 gain -> 9-kernel chain
// is launch/boundary-overhead-bound (~10-15us x 9), not cold-weight-bound.
// R8 showed cg::grid.sync = ~40us each (device-scope fence -> L2 wb/inv x8
// XCDs). R10: R8's verified 9-phase structure, but cross-phase ws traffic
// uses RELAXED AGENT-SCOPE atomics (sc1, device-coherent point, no flush)
// and the grid barrier is a relaxed agent-scope counter + spin. Ordering:
// __syncthreads() drains vmcnt before s_barrier, so data stores are globally
// visible before the tid0 arrival increment issues. Counters zeroed by a
// captured 32B hipMemsetAsync each iteration (harness poisons ws).
//
// Output layout (flat f32): rendered@0, mu@100352, logvar@108544,
// cp@116736, widths@124928, alphas@125184.
// ---------------------------------------------------------------------------

#define O_MU  100352
#define O_LV  108544
#define O_CP  116736
#define O_WD  124928
#define O_AL  125184

// workspace float offsets
#define W_H1   0        // h1_T  [256][128]
#define W_HE   32768    // he_T  [256][128]
#define W_MUT  65536    // mu_T  [64][128]
#define W_LVT  73728    // lv_T  [64][128]
#define W_D1   81920    // d1_T  [512][128]
#define W_H2   147456   // h2_T  [512][128]
#define W_PN   212992   // pn_T  [28][128]
#define W_R1Z  216576   // r1z_T [512][128]
#define W_R1   282112   // r1_T  [512][128]
#define W_PT   347648   // P_T   [52][128]
#define W_WA   354304   // wa_T  [4][128]
#define W_BAR  354816   // 8 unsigned barrier counters
#define NBLK   256

__device__ __forceinline__ float leaky(float x) { return x >= 0.f ? x : 0.2f * x; }
__device__ __forceinline__ float seluf(float x) {
    const float s = 1.0507009873554805f, a = 1.6732632423543772f;
    return x > 0.f ? s * x : s * (a * expm1f(x));
}
__device__ __forceinline__ float sigm(float x) { return 1.f / (1.f + expf(-x)); }

// device-coherent (agent-scope, relaxed) ws accessors — sc1 path, no flush
__device__ __forceinline__ float ldws(const float* p) {
    return __hip_atomic_load((const float*)p, __ATOMIC_RELAXED, __HIP_MEMORY_SCOPE_AGENT);
}
__device__ __forceinline__ void stws(float* p, float v) {
    __hip_atomic_store(p, v, __ATOMIC_RELAXED, __HIP_MEMORY_SCOPE_AGENT);
}

// light grid barrier: relaxed agent atomic counter + spin. Data ordering:
// __syncthreads() drains each wave's vmcnt (stores acked at coherent point)
// before tid0's increment issues.
__device__ __forceinline__ void gbar(unsigned* c) {
    __syncthreads();
    if (threadIdx.x == 0) {
        __hip_atomic_fetch_add(c, 1u, __ATOMIC_RELAXED, __HIP_MEMORY_SCOPE_AGENT);
        while (__hip_atomic_load(c, __ATOMIC_RELAXED, __HIP_MEMORY_SCOPE_AGENT) < NBLK)
            __builtin_amdgcn_s_sleep(2);
    }
    __syncthreads();
}

__global__ __launch_bounds__(512)
void vae_fused(const float* __restrict__ x, const float* __restrict__ eps,
               const float* __restrict__ enc_w1, const float* __restrict__ enc_b1,
               const float* __restrict__ enc_w2, const float* __restrict__ enc_b2,
               const float* __restrict__ mu_w, const float* __restrict__ mu_b,
               const float* __restrict__ lv_w, const float* __restrict__ lv_b,
               const float* __restrict__ dec_w1, const float* __restrict__ dec_b1,
               const float* __restrict__ dec_w2, const float* __restrict__ dec_b2,
               const float* __restrict__ cp_w, const float* __restrict__ cp_b,
               const float* __restrict__ ref_w1, const float* __restrict__ ref_b1,
               const float* __restrict__ ref_w2, const float* __restrict__ ref_b2,
               const float* __restrict__ wd_w, const float* __restrict__ wd_b,
               const float* __restrict__ al_w, const float* __restrict__ al_b,
               float* __restrict__ out, float* __restrict__ ws) {
    __shared__ float part[4][2][128];
    __shared__ float sP[56];
    __shared__ float sWA[4];
    __shared__ float sQ[128];

    const int b = blockIdx.x;
    const int L = (b & 7) * 32 + (b >> 3);   // bijective XCD remap (256 = 8*32)
    const int tid = threadIdx.x;
    const int r = tid & 127;                 // batch row
    const int ks = tid >> 7;                 // K-slice 0..3

    float* const h1T  = ws + W_H1;
    float* const heT  = ws + W_HE;
    float* const muT  = ws + W_MUT;
    float* const lvT  = ws + W_LVT;
    float* const d1T  = ws + W_D1;
    float* const h2T  = ws + W_H2;
    float* const pnT  = ws + W_PN;
    float* const r1zT = ws + W_R1Z;
    float* const r1T  = ws + W_R1;
    float* const PT   = ws + W_PT;
    float* const waT  = ws + W_WA;
    unsigned* const bar = (unsigned*)(ws + W_BAR);

    // ---- prefetch later-stage weight lines (consumed after enc1 issues)
    float pf = 0.f;
    {
        const int j0 = 2 * L;
        pf += dec_w2[tid * 512 + j0];
        if (tid < 92)  pf += ref_w1[tid * 512 + j0];
        if (tid < 64)  pf += dec_w1[tid * 512 + j0];
        if (tid < 256) pf += enc_w2[tid * 256 + L];
        if (b < 128 && tid < 256)
            pf += (b >= 64 ? lv_w : mu_w)[tid * 64 + (b & 63)];
        if (b < 28)    pf += cp_w[tid * 28 + b];
        if (b < 52)    pf += ref_w2[tid * 52 + b];
    }

    // ================= phase 1: enc1 (j = L, K=784, slice 196) =================
    {
        const float* __restrict__ xr = x + r * 784;
        const int k0 = ks * 196;
        float acc = 0.f;
#pragma unroll 4
        for (int i = 0; i < 196; i++)
            acc = fmaf(xr[k0 + i], enc_w1[(k0 + i) * 256 + L], acc);
        asm volatile("" :: "v"(pf));
        part[ks][0][r] = acc;
    }
    __syncthreads();
    if (tid < 128) {
        float s = enc_b1[L];
#pragma unroll
        for (int q = 0; q < 4; q++) s += part[q][0][tid];
        stws(h1T + L * 128 + tid, leaky(s));
    }
    gbar(bar + 0);

    // ================= phase 2: enc2 (j = L, K=256, slice 64) ==================
    {
        const int k0 = ks * 64;
        float acc = 0.f;
#pragma unroll 8
        for (int i = 0; i < 64; i++)
            acc = fmaf(ldws(h1T + (k0 + i) * 128 + r), enc_w2[(k0 + i) * 256 + L], acc);
        part[ks][0][r] = acc;
    }
    __syncthreads();
    if (tid < 128) {
        float s = enc_b2[L];
#pragma unroll
        for (int q = 0; q < 4; q++) s += part[q][0][tid];
        stws(heT + L * 128 + tid, leaky(s));
    }
    gbar(bar + 1);

    // ================= phase 3: mu|lv (blocks b<128, K=256, slice 64) ==========
    if (b < 128) {
        const int head = b >> 6, col = b & 63;
        const float* __restrict__ w = head ? lv_w : mu_w;
        const int k0 = ks * 64;
        float acc = 0.f;
#pragma unroll 8
        for (int i = 0; i < 64; i++)
            acc = fmaf(ldws(heT + (k0 + i) * 128 + r), w[(k0 + i) * 64 + col], acc);
        part[ks][0][r] = acc;
        __syncthreads();
        if (tid < 128) {
            float s = (head ? lv_b : mu_b)[col];
#pragma unroll
            for (int q = 0; q < 4; q++) s += part[q][0][tid];
            stws((head ? lvT : muT) + col * 128 + tid, s);
            out[(head ? O_LV : O_MU) + tid * 64 + col] = s;
        }
    }
    gbar(bar + 2);

    // ================= phase 4: dec1 (cols 2L,2L+1, K=64, slice 16) ============
    {
        const int j0 = 2 * L, k0 = ks * 16;
        float a0 = 0.f, a1 = 0.f;
#pragma unroll
        for (int i = 0; i < 16; i++) {
            const int k = k0 + i;
            float zv = fmaf(eps[r * 64 + k], expf(0.5f * ldws(lvT + k * 128 + r)),
                            ldws(muT + k * 128 + r));
            a0 = fmaf(zv, dec_w1[k * 512 + j0],     a0);
            a1 = fmaf(zv, dec_w1[k * 512 + j0 + 1], a1);
        }
        part[ks][0][r] = a0; part[ks][1][r] = a1;
    }
    __syncthreads();
    if (tid < 256) {
        const int c = tid >> 7, ll = tid & 127;
        float s = dec_b1[2 * L + c];
#pragma unroll
        for (int q = 0; q < 4; q++) s += part[q][c][ll];
        stws(d1T + (2 * L + c) * 128 + ll, seluf(s));
    }
    gbar(bar + 3);

    // ================= phase 5: dec2 (cols 2L,2L+1, K=512, slice 128) ==========
    {
        const int j0 = 2 * L, k0 = ks * 128;
        float a0 = 0.f, a1 = 0.f;
#pragma unroll 4
        for (int i = 0; i < 128; i++) {
            const float v = ldws(d1T + (k0 + i) * 128 + r);
            a0 = fmaf(v, dec_w2[(k0 + i) * 512 + j0],     a0);
            a1 = fmaf(v, dec_w2[(k0 + i) * 512 + j0 + 1], a1);
        }
        part[ks][0][r] = a0; part[ks][1][r] = a1;
    }
    __syncthreads();
    if (tid < 256) {
        const int c = tid >> 7, ll = tid & 127;
        float s = dec_b2[2 * L + c];
#pragma unroll
        for (int q = 0; q < 4; q++) s += part[q][c][ll];
        stws(h2T + (2 * L + c) * 128 + ll, seluf(s));
    }
    gbar(bar + 4);

    // ========== phase 6: ref1 z-part (all blocks) + heads (b<32) ==============
    {
        const int j0 = 2 * L, k0 = ks * 16;
        float a0 = 0.f, a1 = 0.f;
#pragma unroll
        for (int i = 0; i < 16; i++) {
            const int k = k0 + i;
            float zv = fmaf(eps[r * 64 + k], expf(0.5f * ldws(lvT + k * 128 + r)),
                            ldws(muT + k * 128 + r));
            a0 = fmaf(zv, ref_w1[k * 512 + j0],     a0);
            a1 = fmaf(zv, ref_w1[k * 512 + j0 + 1], a1);
        }
        part[ks][0][r] = a0; part[ks][1][r] = a1;
    }
    __syncthreads();
    if (tid < 256) {
        const int c = tid >> 7, ll = tid & 127;
        float s = 0.f;
#pragma unroll
        for (int q = 0; q < 4; q++) s += part[q][c][ll];
        stws(r1zT + (2 * L + c) * 128 + ll, s);
    }
    __syncthreads();
    if (b < 32) {
        const float* __restrict__ w; int ldw, col;
        if (b < 28)      { w = cp_w; ldw = 28; col = b; }
        else if (b < 30) { w = wd_w; ldw = 2;  col = b - 28; }
        else             { w = al_w; ldw = 2;  col = b - 30; }
        const int k0 = ks * 128;
        float acc = 0.f;
#pragma unroll 4
        for (int i = 0; i < 128; i++)
            acc = fmaf(ldws(h2T + (k0 + i) * 128 + r), w[(k0 + i) * ldw + col], acc);
        part[ks][0][r] = acc;
        __syncthreads();
        if (tid < 128) {
            float s = 0.f;
#pragma unroll
            for (int q = 0; q < 4; q++) s += part[q][0][tid];
            if (b < 28) {
                stws(pnT + b * 128 + tid, tanhf(s + cp_b[col]));
            } else if (b < 30) {
                float v = fmaf(sigm(s + wd_b[col]), 2.f, 1.f);
                out[O_WD + tid * 2 + col] = v; stws(waT + col * 128 + tid, v);
            } else {
                float v = sigm(s + al_b[col]);
                out[O_AL + tid * 2 + col] = v; stws(waT + (2 + col) * 128 + tid, v);
            }
        }
    }
    gbar(bar + 5);

    // ================= phase 7: ref1 pn-part + combine (K=28, slice 7) =========
    {
        const int j0 = 2 * L, k0 = 64 + ks * 7;
        float a0 = 0.f, a1 = 0.f;
#pragma unroll
        for (int i = 0; i < 7; i++) {
            const int k = k0 + i;
            const float v = ldws(pnT + (k - 64) * 128 + r);
            a0 = fmaf(v, ref_w1[k * 512 + j0],     a0);
            a1 = fmaf(v, ref_w1[k * 512 + j0 + 1], a1);
        }
        part[ks][0][r] = a0; part[ks][1][r] = a1;
    }
    __syncthreads();
    if (tid < 256) {
        const int c = tid >> 7, ll = tid & 127;
        float s = ref_b1[2 * L + c] + ldws(r1zT + (2 * L + c) * 128 + ll);
#pragma unroll
        for (int q = 0; q < 4; q++) s += part[q][c][ll];
        stws(r1T + (2 * L + c) * 128 + ll, seluf(s));
    }
    gbar(bar + 6);

    // ================= phase 8: ref2 (blocks b<52, K=512, slice 128) ===========
    if (b < 52) {
        const int k0 = ks * 128;
        float acc = 0.f;
#pragma unroll 4
        for (int i = 0; i < 128; i++)
            acc = fmaf(ldws(r1T + (k0 + i) * 128 + r), ref_w2[(k0 + i) * 52 + b], acc);
        part[ks][0][r] = acc;
        __syncthreads();
        if (tid < 128) {
            float s = ref_b2[b];
#pragma unroll
            for (int q = 0; q < 4; q++) s += part[q][0][tid];
            stws(PT + b * 128 + tid, fmaf(tanhf(s), 12.f, 14.f));
        }
    }
    gbar(bar + 7);

    // ================= phase 9: raster (row = b>>1, half = b&1) ================
    {
        const int row = b >> 1, half = b & 1;
        if (tid < 52) sP[tid] = ldws(PT + tid * 128 + row);
        if (tid >= 64 && tid < 68) sWA[tid - 64] = ldws(waT + (tid - 64) * 128 + row);
        __syncthreads();
        if (half == 0 && tid < 64) {
            const int idx = tid, p = idx >> 5, rest = idx & 31;
            const int s = rest >> 3, kk = (rest >> 1) & 3, d = idx & 1;
            out[O_CP + row * 64 + idx] = sP[p * 26 + (3 * s + kk) * 2 + d];
        }
        if (tid < 128) {
            const int idx = tid, p = idx >> 6, s = (idx >> 4) & 3, ti = (idx >> 1) & 7, d = idx & 1;
            const float t = (float)ti / 7.0f, mt = 1.0f - t;
            const float c0 = mt * mt * mt, c1 = 3.f * mt * mt * t;
            const float c2 = 3.f * mt * t * t, c3 = t * t * t;
            const float* base = sP + p * 26 + 6 * s + d;
            sQ[idx] = c0 * base[0] + c1 * base[2] + c2 * base[4] + c3 * base[6];
        }
        __syncthreads();
        const float2* __restrict__ sQ2 = (const float2*)sQ;
        for (int u = tid; u < 1568; u += 512) {
            const int pixel = half * 392 + (u >> 2);
            const int sub = u & 3;
            const int py = pixel / 28, px = pixel - py * 28;
            const float sy = ((float)(2 * py + (sub >> 1)) + 0.5f) * 0.5f;
            const float sx = ((float)(2 * px + (sub & 1)) + 0.5f) * 0.5f;
            float img = 1.0f;
#pragma unroll
            for (int p = 0; p < 2; p++) {
                float dmin2 = 1e30f;
                int cnt = 0;
                float2 cur = sQ2[p * 32];
                bool bp = cur.y > sy;
#pragma unroll
                for (int m = 0; m < 32; m++) {
                    float2 nxt = sQ2[p * 32 + ((m + 1) & 31)];
                    float dx = sx - cur.x;
                    float dy = sy - cur.y;
                    dmin2 = fminf(dmin2, fmaf(dx, dx, dy * dy));
                    bool bn = nxt.y > sy;
                    float den = nxt.y - cur.y + 1e-8f;
                    float lhs = dx * den;
                    float rhs = dy * (nxt.x - cur.x);
                    if ((bp != bn) && ((lhs < rhs) == (den > 0.0f))) cnt++;
                    cur = nxt;
                    bp = bn;
                }
                float dist = sqrtf(dmin2);
                float stroke = fminf(fmaxf(fmaf(sWA[p], 0.5f, 0.5f) - dist, 0.f), 1.f);
                float cov = fmaxf((float)(cnt & 1), stroke);
                img *= fmaf(-sWA[2 + p], cov, 1.0f);
            }
            img += __shfl_xor(img, 1);
            img += __shfl_xor(img, 2);
            if (sub == 0) out[row * 784 + pixel] = 1.0f - 0.25f * img;
        }
    }
}

extern "C" void kernel_launch(void* const* d_in, const int* in_sizes, int n_in,
                              void* d_out, int out_size, void* d_ws, size_t ws_size,
                              hipStream_t stream) {
    const float* x      = (const float*)d_in[0];
    const float* eps    = (const float*)d_in[1];
    const float* enc_w1 = (const float*)d_in[2];
    const float* enc_b1 = (const float*)d_in[3];
    const float* enc_w2 = (const float*)d_in[4];
    const float* enc_b2 = (const float*)d_in[5];
    const float* mu_w   = (const float*)d_in[6];
    const float* mu_b   = (const float*)d_in[7];
    const float* lv_w   = (const float*)d_in[8];
    const float* lv_b   = (const float*)d_in[9];
    const float* dec_w1 = (const float*)d_in[10];
    const float* dec_b1 = (const float*)d_in[11];
    const float* dec_w2 = (const float*)d_in[12];
    const float* dec_b2 = (const float*)d_in[13];
    const float* cp_w   = (const float*)d_in[14];
    const float* cp_b   = (const float*)d_in[15];
    const float* ref_w1 = (const float*)d_in[16];
    const float* ref_b1 = (const float*)d_in[17];
    const float* ref_w2 = (const float*)d_in[18];
    const float* ref_b2 = (const float*)d_in[19];
    const float* wd_w   = (const float*)d_in[20];
    const float* wd_b   = (const float*)d_in[21];
    const float* al_w   = (const float*)d_in[22];
    const float* al_b   = (const float*)d_in[23];

    float* out = (float*)d_out;
    float* ws  = (float*)d_ws;   // needs W_BAR*4 + 32 B ≈ 1.42 MB

    // zero the 8 barrier counters (ws is re-poisoned between iterations)
    hipMemsetAsync(ws + W_BAR, 0, 8 * sizeof(unsigned), stream);

    void* args[] = {
        (void*)&x, (void*)&eps,
        (void*)&enc_w1, (void*)&enc_b1, (void*)&enc_w2, (void*)&enc_b2,
        (void*)&mu_w, (void*)&mu_b, (void*)&lv_w, (void*)&lv_b,
        (void*)&dec_w1, (void*)&dec_b1, (void*)&dec_w2, (void*)&dec_b2,
        (void*)&cp_w, (void*)&cp_b, (void*)&ref_w1, (void*)&ref_b1,
        (void*)&ref_w2, (void*)&ref_b2, (void*)&wd_w, (void*)&wd_b,
        (void*)&al_w, (void*)&al_b, (void*)&out, (void*)&ws
    };
    hipLaunchCooperativeKernel((void*)vae_fused, dim3(256), dim3(512),
                               args, 0, stream);
}

// Round 5
// 229.648 us; speedup vs baseline: 1.4028x; 1.4028x over previous
//
#include <hip/hip_runtime.h>
#include <math.h>

// ---------------------------------------------------------------------------
// HierarchicalVAE, MI355X (gfx950), fp32 — R11: 4 regular-launch kernels.
// R10 post-mortem: cooperative launch = +100us fixed graph overhead; agent-
// scope (uncached) ws traffic slower than kernel boundaries. Grid-wide sync
// in ANY form loses to plain launch boundaries on this chip.
// Model: dur ~= harness fills (~80us, fixed) + kernels + ~10-15us/boundary.
// R11: cut 9 kernels -> 4. Fuse stages whose block can own ROWS (LDS carries
// the intermediate, no cross-block dep): mid = enc2+mulv+z+dec1 (1 row/blk),
// tail = heads+ref1+ref2+raster (half-row/blk, MLP duplicated per half).
// enc1/dec2 stay wide (512 blocks, R7-verified code).
//
// Output layout (flat f32): rendered@0, mu@100352, logvar@108544,
// cp@116736, widths@124928, alphas@125184.
// ---------------------------------------------------------------------------

#define O_MU  100352
#define O_LV  108544
#define O_CP  116736
#define O_WD  124928
#define O_AL  125184

// workspace float offsets (total 180224 floats = 721 KB)
#define W_H1   0        // h1_T  [256][128]
#define W_MUT  32768    // mu_T  [64][128]
#define W_LVT  40960    // lv_T  [64][128]
#define W_D1   49152    // d1_T  [512][128]
#define W_H2   114688   // h2_T  [512][128]

__device__ __forceinline__ float leaky(float x) { return x >= 0.f ? x : 0.2f * x; }
__device__ __forceinline__ float seluf(float x) {
    const float s = 1.0507009873554805f, a = 1.6732632423543772f;
    return x > 0.f ? s * x : s * (a * expm1f(x));
}
__device__ __forceinline__ float sigm(float x) { return 1.f / (1.f + expf(-x)); }

// ---- enc1: h1_T = leaky(x @ enc_w1 + b). grid 512: j=bid>>1, h=bid&1. (R7)
__global__ __launch_bounds__(512)
void enc1_k(const float* __restrict__ x, const float* __restrict__ w,
            const float* __restrict__ b, float* __restrict__ outT) {
    __shared__ float part[8][64];
    const int j = blockIdx.x >> 1, h = blockIdx.x & 1;
    const int tid = threadIdx.x, lane = tid & 63, ks = tid >> 6;
    const int r = h * 64 + lane;
    const float* __restrict__ xr = x + r * 784;
    float acc = 0.f;
    const int k0 = ks * 98;
#pragma unroll 7
    for (int i = 0; i < 98; i++)
        acc = fmaf(xr[k0 + i], w[(k0 + i) * 256 + j], acc);
    part[ks][lane] = acc;
    __syncthreads();
    if (tid < 64) {
        float s = b[j];
#pragma unroll
        for (int q = 0; q < 8; q++) s += part[q][tid];
        outT[j * 128 + h * 64 + tid] = leaky(s);
    }
}

// ---- mid: enc2 + mu/lv + z + dec1, block = 1 row (grid 128).
__global__ __launch_bounds__(512)
void mid_k(const float* __restrict__ h1T,
           const float* __restrict__ enc_w2, const float* __restrict__ enc_b2,
           const float* __restrict__ mu_w, const float* __restrict__ mu_b,
           const float* __restrict__ lv_w, const float* __restrict__ lv_b,
           const float* __restrict__ eps,
           const float* __restrict__ dec_w1, const float* __restrict__ dec_b1,
           float* __restrict__ muT, float* __restrict__ lvT,
           float* __restrict__ d1T, float* __restrict__ out) {
    __shared__ float sh1[256], she[256], sml[128], sz[64];
    const int row = blockIdx.x, tid = threadIdx.x;
    if (tid < 256) sh1[tid] = h1T[tid * 128 + row];
    __syncthreads();
    // enc2: 256 outs x 2 lanes, K-slice 128
    {
        const int o = tid >> 1, g = tid & 1;
        float acc = 0.f;
        const int k0 = g * 128;
#pragma unroll 8
        for (int i = 0; i < 128; i++)
            acc = fmaf(sh1[k0 + i], enc_w2[(k0 + i) * 256 + o], acc);
        acc += __shfl_xor(acc, 1);
        if (g == 0) she[o] = leaky(acc + enc_b2[o]);
    }
    __syncthreads();
    // mu|lv: 128 outs (o<64 mu, else lv) x 4 lanes, K-slice 64
    {
        const int o = tid >> 2, g = tid & 3;
        const float* __restrict__ w = (o < 64) ? mu_w : lv_w;
        const int col = o & 63;
        float acc = 0.f;
        const int k0 = g * 64;
#pragma unroll 8
        for (int i = 0; i < 64; i++)
            acc = fmaf(she[k0 + i], w[(k0 + i) * 64 + col], acc);
        acc += __shfl_xor(acc, 1);
        acc += __shfl_xor(acc, 2);
        if (g == 0) {
            float s = acc + ((o < 64) ? mu_b : lv_b)[col];
            sml[o] = s;
            ((o < 64) ? muT : lvT)[col * 128 + row] = s;
            out[((o < 64) ? O_MU : O_LV) + row * 64 + col] = s;
        }
    }
    __syncthreads();
    if (tid < 64)
        sz[tid] = fmaf(eps[row * 64 + tid], expf(0.5f * sml[64 + tid]), sml[tid]);
    __syncthreads();
    // dec1: 512 outs x 1 lane, K=64
    {
        float acc = 0.f;
#pragma unroll 8
        for (int k = 0; k < 64; k++)
            acc = fmaf(sz[k], dec_w1[k * 512 + tid], acc);
        d1T[tid * 128 + row] = seluf(acc + dec_b1[tid]);
    }
}

// ---- dec2: h2_T = selu(d1 @ dec_w2 + b). grid 512, 2 cols, slice 64. (R7)
__global__ __launch_bounds__(512)
void dec2_k(const float* __restrict__ inT, const float* __restrict__ w,
            const float* __restrict__ b, float* __restrict__ outT) {
    __shared__ float part[8][2][64];
    const int j0 = (blockIdx.x >> 1) * 2, h = blockIdx.x & 1;
    const int tid = threadIdx.x, lane = tid & 63, ks = tid >> 6;
    const int r = h * 64 + lane;
    float a0 = 0.f, a1 = 0.f;
    const int k0 = ks * 64;
#pragma unroll 4
    for (int i = 0; i < 64; i++) {
        const float v = inT[(k0 + i) * 128 + r];
        a0 = fmaf(v, w[(k0 + i) * 512 + j0],     a0);
        a1 = fmaf(v, w[(k0 + i) * 512 + j0 + 1], a1);
    }
    part[ks][0][lane] = a0; part[ks][1][lane] = a1;
    __syncthreads();
    if (tid < 128) {
        const int c = tid >> 6, ll = tid & 63;
        float s = b[j0 + c];
#pragma unroll
        for (int q = 0; q < 8; q++) s += part[q][c][ll];
        outT[(j0 + c) * 128 + h * 64 + ll] = seluf(s);
    }
}

// ---- tail: heads + ref1 + ref2 + raster. grid 256: row=bid>>1, half=bid&1.
// MLP parts duplicated per half (cheap); raster split by half.
__global__ __launch_bounds__(512)
void tail_k(const float* __restrict__ h2T, const float* __restrict__ muT,
            const float* __restrict__ lvT, const float* __restrict__ eps,
            const float* __restrict__ cp_w, const float* __restrict__ cp_b,
            const float* __restrict__ wd_w, const float* __restrict__ wd_b,
            const float* __restrict__ al_w, const float* __restrict__ al_b,
            const float* __restrict__ ref_w1, const float* __restrict__ ref_b1,
            const float* __restrict__ ref_w2, const float* __restrict__ ref_b2,
            float* __restrict__ out) {
    __shared__ float sh2[512];
    __shared__ float sIn[96];    // z(64) | pn(28)
    __shared__ float sR1[512];
    __shared__ float sP[56];
    __shared__ float sWA[4];
    __shared__ float sQ[128];
    const int row = blockIdx.x >> 1, half = blockIdx.x & 1;
    const int tid = threadIdx.x;

    sh2[tid] = h2T[tid * 128 + row];
    if (tid < 64) {
        float mu = muT[tid * 128 + row], lv = lvT[tid * 128 + row];
        sIn[tid] = fmaf(eps[row * 64 + tid], expf(0.5f * lv), mu);
    }
    __syncthreads();

    // heads: 32 outputs x 16 lanes, K=512 (R6-verified pattern)
    {
        const int o = tid >> 4, g = tid & 15;
        const float* __restrict__ w; int ldw, col;
        if (o < 28)      { w = cp_w; ldw = 28; col = o; }
        else if (o < 30) { w = wd_w; ldw = 2;  col = o - 28; }
        else             { w = al_w; ldw = 2;  col = o - 30; }
        float acc = 0.f;
        for (int k = g; k < 512; k += 16) acc = fmaf(sh2[k], w[k * ldw + col], acc);
        acc += __shfl_xor(acc, 1);
        acc += __shfl_xor(acc, 2);
        acc += __shfl_xor(acc, 4);
        acc += __shfl_xor(acc, 8);
        if (g == 0) {
            if (o < 28) {
                sIn[64 + o] = tanhf(acc + cp_b[col]);
            } else if (o < 30) {
                float v = fmaf(sigm(acc + wd_b[col]), 2.f, 1.f);
                if (half == 0) out[O_WD + row * 2 + col] = v;
                sWA[col] = v;
            } else {
                float v = sigm(acc + al_b[col]);
                if (half == 0) out[O_AL + row * 2 + col] = v;
                sWA[2 + col] = v;
            }
        }
    }
    __syncthreads();

    // ref1: j = tid, K = 92
    {
        float acc = 0.f;
#pragma unroll 4
        for (int k = 0; k < 92; k++)
            acc = fmaf(sIn[k], ref_w1[k * 512 + tid], acc);
        sR1[tid] = seluf(acc + ref_b1[tid]);
    }
    __syncthreads();

    // ref2: 52 outputs x 8 lanes, K=512 (R6-verified pattern)
    {
        const int o = tid >> 3, g = tid & 7;
        float acc = 0.f;
        if (o < 52)
            for (int k = g; k < 512; k += 8) acc = fmaf(sR1[k], ref_w2[k * 52 + o], acc);
        acc += __shfl_xor(acc, 1);
        acc += __shfl_xor(acc, 2);
        acc += __shfl_xor(acc, 4);
        if (g == 0 && o < 52)
            sP[o] = fmaf(tanhf(acc + ref_b2[o]), 12.f, 14.f);
    }
    __syncthreads();

    // control_points out (half 0 only) + bezier polyline
    if (half == 0 && tid < 64) {
        const int idx = tid, p = idx >> 5, rest = idx & 31;
        const int s = rest >> 3, kk = (rest >> 1) & 3, d = idx & 1;
        out[O_CP + row * 64 + idx] = sP[p * 26 + (3 * s + kk) * 2 + d];
    }
    if (tid < 128) {
        const int idx = tid, p = idx >> 6, s = (idx >> 4) & 3, ti = (idx >> 1) & 7, d = idx & 1;
        const float t = (float)ti / 7.0f, mt = 1.0f - t;
        const float c0 = mt * mt * mt, c1 = 3.f * mt * mt * t;
        const float c2 = 3.f * mt * t * t, c3 = t * t * t;
        const float* base = sP + p * 26 + 6 * s + d;
        sQ[idx] = c0 * base[0] + c1 * base[2] + c2 * base[4] + c3 * base[6];
    }
    __syncthreads();

    // raster: this half's 392 pixels x 4 AA = 1568 units
    const float2* __restrict__ sQ2 = (const float2*)sQ;
    for (int u = tid; u < 1568; u += 512) {
        const int pixel = half * 392 + (u >> 2);
        const int sub = u & 3;
        const int py = pixel / 28, px = pixel - py * 28;
        const float sy = ((float)(2 * py + (sub >> 1)) + 0.5f) * 0.5f;
        const float sx = ((float)(2 * px + (sub & 1)) + 0.5f) * 0.5f;
        float img = 1.0f;
#pragma unroll
        for (int p = 0; p < 2; p++) {
            float dmin2 = 1e30f;
            int cnt = 0;
            float2 cur = sQ2[p * 32];
            bool bp = cur.y > sy;
#pragma unroll
            for (int m = 0; m < 32; m++) {
                float2 nxt = sQ2[p * 32 + ((m + 1) & 31)];
                float dx = sx - cur.x;
                float dy = sy - cur.y;
                dmin2 = fminf(dmin2, fmaf(dx, dx, dy * dy));
                bool bn = nxt.y > sy;
                float den = nxt.y - cur.y + 1e-8f;
                float lhs = dx * den;
                float rhs = dy * (nxt.x - cur.x);
                if ((bp != bn) && ((lhs < rhs) == (den > 0.0f))) cnt++;
                cur = nxt;
                bp = bn;
            }
            float dist = sqrtf(dmin2);
            float stroke = fminf(fmaxf(fmaf(sWA[p], 0.5f, 0.5f) - dist, 0.f), 1.f);
            float cov = fmaxf((float)(cnt & 1), stroke);
            img *= fmaf(-sWA[2 + p], cov, 1.0f);
        }
        img += __shfl_xor(img, 1);
        img += __shfl_xor(img, 2);
        if (sub == 0) out[row * 784 + pixel] = 1.0f - 0.25f * img;
    }
}

extern "C" void kernel_launch(void* const* d_in, const int* in_sizes, int n_in,
                              void* d_out, int out_size, void* d_ws, size_t ws_size,
                              hipStream_t stream) {
    const float* x      = (const float*)d_in[0];
    const float* eps    = (const float*)d_in[1];
    const float* enc_w1 = (const float*)d_in[2];
    const float* enc_b1 = (const float*)d_in[3];
    const float* enc_w2 = (const float*)d_in[4];
    const float* enc_b2 = (const float*)d_in[5];
    const float* mu_w   = (const float*)d_in[6];
    const float* mu_b   = (const float*)d_in[7];
    const float* lv_w   = (const float*)d_in[8];
    const float* lv_b   = (const float*)d_in[9];
    const float* dec_w1 = (const float*)d_in[10];
    const float* dec_b1 = (const float*)d_in[11];
    const float* dec_w2 = (const float*)d_in[12];
    const float* dec_b2 = (const float*)d_in[13];
    const float* cp_w   = (const float*)d_in[14];
    const float* cp_b   = (const float*)d_in[15];
    const float* ref_w1 = (const float*)d_in[16];
    const float* ref_b1 = (const float*)d_in[17];
    const float* ref_w2 = (const float*)d_in[18];
    const float* ref_b2 = (const float*)d_in[19];
    const float* wd_w   = (const float*)d_in[20];
    const float* wd_b   = (const float*)d_in[21];
    const float* al_w   = (const float*)d_in[22];
    const float* al_b   = (const float*)d_in[23];

    float* out = (float*)d_out;
    float* ws  = (float*)d_ws;   // needs 180224 floats = 721 KB

    enc1_k<<<512, 512, 0, stream>>>(x, enc_w1, enc_b1, ws + W_H1);
    mid_k <<<128, 512, 0, stream>>>(ws + W_H1, enc_w2, enc_b2,
                                    mu_w, mu_b, lv_w, lv_b, eps,
                                    dec_w1, dec_b1,
                                    ws + W_MUT, ws + W_LVT, ws + W_D1, out);
    dec2_k<<<512, 512, 0, stream>>>(ws + W_D1, dec_w2, dec_b2, ws + W_H2);
    tail_k<<<256, 512, 0, stream>>>(ws + W_H2, ws + W_MUT, ws + W_LVT, eps,
                                    cp_w, cp_b, wd_w, wd_b, al_w, al_b,
                                    ref_w1, ref_b1, ref_w2, ref_b2, out);
}